// Round 5
// baseline (359.578 us; speedup 1.0000x reference)
//
#include <hip/hip_runtime.h>
#include <hip/hip_bf16.h>

// FlowNetC correlation, two-pass, barrier-free MFMA.
// Pass 1: in2 NCHW fp32 -> padded NHWC bf16 (rows -4..99, px -8..135, zeros in pad).
// Pass 2: out[b,(dy+4)*9+(dx+4),y,x] = (1/256)*sum_c in1*in2_shift via 16x16x32 bf16
//         MFMA with A-frags gathered from NCHW fp32 and B-frags as single b128
//         loads from the padded NHWC copy. No LDS, no __syncthreads.

#define H_ 96
#define W_ 128
#define HW_ 12288
#define CHW_ 3145728
#define Y2 104                      // 4 + 96 + 4 padded rows
#define X2 144                      // 8 + 128 + 8 padded px
#define ROWB 73728                  // X2 * 256ch * 2B
#define PLANEB 7667712ULL           // Y2 * ROWB
#define WS_NEEDED 61341696ULL       // 8 * PLANEB

typedef __attribute__((ext_vector_type(8))) short short8;
typedef __attribute__((ext_vector_type(4))) float f32x4;

// ---------------- pass 1: convert + pad in2 ----------------
__global__ __launch_bounds__(256) void cvt_in2(
    const float* __restrict__ in2, char* __restrict__ in2t)
{
    int idx = blockIdx.x * 256 + threadIdx.x;   // 8*104*32*144 = 3,833,856
    int px2 = idx % X2;
    int r   = idx / X2;
    int cg  = r & 31;               // channel group: 8 ch = 16 B
    r >>= 5;
    int yp  = r % Y2;
    int b   = r / Y2;

    short8 v = short8{0, 0, 0, 0, 0, 0, 0, 0};
    const int gx = px2 - 8, gy = yp - 4;
    if (gx >= 0 && gx < W_ && gy >= 0 && gy < H_) {
        const float* sp = in2 + (size_t)b * CHW_ + (size_t)(cg * 8) * HW_
                              + (size_t)gy * W_ + gx;
        union { __hip_bfloat162 h2[4]; short8 s8; } u;
        #pragma unroll
        for (int j = 0; j < 4; ++j) {
            float2 f{ sp[(size_t)(2 * j) * HW_], sp[(size_t)(2 * j + 1) * HW_] };
            u.h2[j] = __float22bfloat162_rn(f);
        }
        v = u.s8;
    }
    *(short8*)(in2t + (size_t)b * PLANEB + (size_t)yp * ROWB
                    + (size_t)px2 * 512 + cg * 16) = v;
}

// ---------------- pass 2: barrier-free banded MFMA ----------------
__global__ __launch_bounds__(512) void corr_pass2(
    const float* __restrict__ in1,
    const char*  __restrict__ in2t,
    float* __restrict__ out)
{
    const int tid = threadIdx.x;
    const int blk = blockIdx.x;        // 1536
    const int b   = blk & 7;           // XCD-affine batch
    const int i   = blk >> 3;          // consecutive blocks walk y on one XCD
    const int y   = i >> 1;            // 0..95
    const int xh  = i & 1;

    const int lane = tid & 63;
    const int wv   = tid >> 6;         // 0..7
    const int mt   = wv >> 1;          // 0..3  (16-px m-tile)
    const int ut   = wv & 1;           // u-half: u0 = x0 - 8 + 16*ut
    const int ln   = lane & 15;
    const int qd   = lane >> 4;
    const int x0   = xh * 64 + mt * 16;

    // A: pixel x0+ln, channels kc*32 + qd*8 + j (fp32 NCHW, 8 strided scalars)
    const float* Ab = in1 + (size_t)b * CHW_ + (size_t)(qd * 8) * HW_
                          + (size_t)y * W_ + (x0 + ln);
    // B: padded NHWC bf16; row yp = (y+s-4)+4 = y+s; px upad = u+8
    const int upad = x0 + 16 * ut + ln;            // 0..143, never OOB
    const char* Bb = in2t + (size_t)b * PLANEB + (size_t)y * ROWB
                          + (size_t)upad * 512 + qd * 16;

    f32x4 acc[9];
    #pragma unroll
    for (int s = 0; s < 9; ++s) acc[s] = f32x4{0.f, 0.f, 0.f, 0.f};

    #pragma unroll
    for (int kc = 0; kc < 8; ++kc) {
        const float* ap = Ab + (size_t)(kc * 32) * HW_;
        float av[8];
        #pragma unroll
        for (int j = 0; j < 8; ++j) av[j] = ap[(size_t)j * HW_];
        union { __hip_bfloat162 h2[4]; short8 s8; } ua;
        #pragma unroll
        for (int j = 0; j < 4; ++j)
            ua.h2[j] = __float22bfloat162_rn(float2{av[2 * j], av[2 * j + 1]});
        const short8 afr = ua.s8;

        const char* bp = Bb + kc * 64;
        #pragma unroll
        for (int s = 0; s < 9; ++s) {
            short8 bfr = *(const short8*)(bp + (size_t)s * ROWB);
            acc[s] = __builtin_amdgcn_mfma_f32_16x16x32_bf16(afr, bfr, acc[s], 0, 0, 0);
        }
    }

    // epilogue: band extraction (layout m89-verified; passed rounds 2-4)
    const float scale = 1.0f / 256.0f;
    #pragma unroll
    for (int s = 0; s < 9; ++s) {
        #pragma unroll
        for (int r = 0; r < 4; ++r) {
            const int m  = qd * 4 + r;
            const int dx = ln - m - 8 + 16 * ut;
            if (dx >= -4 && dx <= 4) {
                out[(((size_t)b * 81 + (size_t)(s * 9 + dx + 4)) * H_ + y) * W_ + (x0 + m)]
                    = acc[s][r] * scale;
            }
        }
    }
}

// ---------------- fallback (round-3 fused kernel) if ws too small ----------------
#define IN2OFF (128 * 64)
#define LDS_BYTES (704 * 64)
__device__ __forceinline__ int grpswz(int g, int p) {
    return ((g ^ (p & 3) ^ ((p >> 2) & 3)) & 3) * 16;
}
__global__ __launch_bounds__(1024, 4) void corr_mfma3(
    const float* __restrict__ in1, const float* __restrict__ in2, float* __restrict__ out)
{
    __shared__ __align__(16) char lds[LDS_BYTES];
    const int tid = threadIdx.x;
    const int blk = blockIdx.x;
    const int b   = blk & 7;
    const int i   = blk >> 3;
    const int yt  = i >> 2;
    const int xq  = i & 3;
    const bool stager = (tid < 704);
    const float* gbase = nullptr;
    bool valid = false;
    int lds_dst0 = 0, kk = 0;
    if (stager) {
        if (tid < 576) {
            const int pq = tid % 144, g = tid / 144;
            const int r = pq / 12, q = pq % 12;
            const int gx = xq * 32 - 8 + 4 * q, ry = yt * 4 - 4 + r;
            valid = (ry >= 0) && (ry < H_) && (gx >= 0) && (gx <= W_ - 4);
            gbase = in2 + (size_t)b * CHW_ + (size_t)(8 * g) * HW_ + ry * W_ + gx;
            lds_dst0 = IN2OFF + (r * 48 + 4 * q) * 64;
            kk = g ^ (q & 3);
        } else {
            const int u1 = tid - 576;
            const int pq = u1 % 32, g = u1 / 32;
            const int r = pq / 8, q = pq % 8;
            const int gx = xq * 32 + 4 * q, yy = yt * 4 + r;
            valid = true;
            gbase = in1 + (size_t)b * CHW_ + (size_t)(8 * g) * HW_ + yy * W_ + gx;
            lds_dst0 = (r * 32 + 4 * q) * 64;
            kk = g ^ (q & 3);
        }
    }
    const int lane = tid & 63, wv = tid >> 6;
    const int xt = wv & 1, ut = (wv >> 1) & 1, yp = wv >> 2;
    const int ln = lane & 15, qd = lane >> 4;
    const int pA = 16 * xt + ln;
    const int offA = (yp * 32 + pA) * 64 + grpswz(qd, pA);
    const int pB = 16 * (xt + ut) + ln;
    const int offB = IN2OFF + (yp * 48 + pB) * 64 + grpswz(qd, pB);
    f32x4 acc[9];
    #pragma unroll
    for (int s = 0; s < 9; ++s) acc[s] = f32x4{0.f, 0.f, 0.f, 0.f};
    float4 pf[8];
    #pragma unroll
    for (int j = 0; j < 8; ++j) pf[j] = float4{0.f, 0.f, 0.f, 0.f};
    if (stager && valid) {
        #pragma unroll
        for (int j = 0; j < 8; ++j) pf[j] = *(const float4*)(gbase + (size_t)j * HW_);
    }
    #pragma unroll
    for (int kc = 0; kc < 8; ++kc) {
        if (kc > 0) __syncthreads();
        if (stager) {
            #pragma unroll
            for (int px = 0; px < 4; ++px) {
                union { __hip_bfloat162 h2[4]; short8 s8; } u;
                #pragma unroll
                for (int jj = 0; jj < 4; ++jj) {
                    float2 f;
                    f.x = ((const float*)&pf[2 * jj])[px];
                    f.y = ((const float*)&pf[2 * jj + 1])[px];
                    u.h2[jj] = __float22bfloat162_rn(f);
                }
                *(short8*)(lds + lds_dst0 + px * 64 + ((kk ^ px) & 3) * 16) = u.s8;
            }
        }
        __syncthreads();
        if (kc < 7 && stager) {
            const float* g2 = gbase + (size_t)(32 * (kc + 1)) * HW_;
            #pragma unroll
            for (int j = 0; j < 8; ++j)
                pf[j] = valid ? *(const float4*)(g2 + (size_t)j * HW_) : float4{0.f, 0.f, 0.f, 0.f};
        }
        short8 afr = *(const short8*)(lds + offA);
        #pragma unroll
        for (int s = 0; s < 9; ++s) {
            short8 bfr = *(const short8*)(lds + offB + s * (48 * 64));
            acc[s] = __builtin_amdgcn_mfma_f32_16x16x32_bf16(afr, bfr, acc[s], 0, 0, 0);
        }
    }
    const float scale = 1.0f / 256.0f;
    const int x0 = xq * 32 + 16 * xt;
    const int y = yt * 4 + yp;
    #pragma unroll
    for (int s = 0; s < 9; ++s) {
        #pragma unroll
        for (int r = 0; r < 4; ++r) {
            const int m = qd * 4 + r;
            const int dx = ln - m - 8 + 16 * ut;
            if (dx >= -4 && dx <= 4)
                out[(((size_t)b * 81 + (size_t)(s * 9 + dx + 4)) * H_ + y) * W_ + (x0 + m)]
                    = acc[s][r] * scale;
        }
    }
}

extern "C" void kernel_launch(void* const* d_in, const int* in_sizes, int n_in,
                              void* d_out, int out_size, void* d_ws, size_t ws_size,
                              hipStream_t stream) {
    const float* in1 = (const float*)d_in[0];
    const float* in2 = (const float*)d_in[1];
    float* out = (float*)d_out;

    if (ws_size >= WS_NEEDED) {
        char* in2t = (char*)d_ws;
        cvt_in2<<<14976, 256, 0, stream>>>(in2, in2t);        // 3,833,856 threads
        corr_pass2<<<1536, 512, 0, stream>>>(in1, in2t, out); // 8b x 96y x 2xh
    } else {
        corr_mfma3<<<768, 1024, 0, stream>>>(in1, in2, out);  // fallback, fused
    }
}